// Round 12
// baseline (436.498 us; speedup 1.0000x reference)
//
#include <hip/hip_runtime.h>

// B=32, S=2048, I=128, H=512, O=64, R=1, ALPHA=0.1  (rank-1 scalar-state RNN)
// DIAGNOSTIC ROUND 2 (amplified ablation): r11's dump-probes were hidden by the
// top-5 duration filter. This round each probe mode RE-EXECUTES its phase 8x
// (idempotent: rewrites identical LDS/global state), so dispatch duration ~=
// ramp + 8*T_phase -- forced into the top-5. Modes: 0=full (correct out),
// 1=ph1 x8, 2=ph1+ph2 x8, 3=ph1+ph2+WPACK+ph3 x8, 4=full with ph4 x8.
// Identification: consecutive Dispatch_Ids within an iteration (0..4).
// Main path (mode 0) is structurally identical to round-10 (116 us, passed).
//   ph1: u[t] = x[t,:].irc for t in [r0-128,r0+256); global_load_lds (16B),
//        counted vmcnt, 3-slot pipeline, per-wave stripes (no syncthreads)
//   ph2: 8 waves x 38-t V-chunks, 86 uniform steps (48 warm-up), scalar VSTEP
//   ph3: w rows [0,304) = relu(V*rp+u*ip) @ W^T via 16x16x32 bf16 MFMA -> sw
//   ph4: y-scan, 8 waves x 32 outputs, 48-step warm-up (w rows t<0 are zero)

#define B_ 32
#define S_ 2048
#define I_ 128
#define H_ 512
#define O_ 64

typedef __attribute__((ext_vector_type(8))) short bf16x8;
typedef __attribute__((ext_vector_type(4))) float f32x4;

__device__ __forceinline__ unsigned short f2bf(float f) {
  unsigned int b = __float_as_uint(f);
  b += 0x7FFFu + ((b >> 16) & 1u);
  return (unsigned short)(b >> 16);
}
__device__ __forceinline__ float bf2f(unsigned short s) {
  return __uint_as_float(((unsigned)s) << 16);
}
__device__ __forceinline__ unsigned pack_bf(float lo, float hi) {
  unsigned a = (__float_as_uint(lo) + 0x8000u) >> 16;
  unsigned b = (__float_as_uint(hi) + 0x8000u) & 0xFFFF0000u;
  return a | b;
}

// DPP add via update_dpp (verified r0-r11). 0x121/2/4/8 = row_ror 1/2/4/8;
// 0x142 = row_bcast15; 0x143 = row_bcast31. ror x4 + bcast15 + bcast31 ->
// lane63 = full 64-lane sum.
#define DPP_ADD(s, CTRL) \
  s += __int_as_float(__builtin_amdgcn_update_dpp(0, __float_as_int(s), CTRL, 0xF, 0xF, true))

#define RL(s, L) __int_as_float(__builtin_amdgcn_readlane(__float_as_int(s), (L)))

// async global->LDS, 16B/lane; LDS dest = uniform base + lane*16 (HW rule)
__device__ __forceinline__ void gload16(const void* g, void* l) {
  __builtin_amdgcn_global_load_lds(
      (const __attribute__((address_space(1))) unsigned int*)g,
      (__attribute__((address_space(3))) unsigned int*)l, 16, 0, 0);
}
#define WAITVM(N) asm volatile("s_waitcnt vmcnt(" #N ")" ::: "memory")
#define SCHEDB() __builtin_amdgcn_sched_barrier(0)

// LDS layout (bytes): su[480]f | sV[384]f | srp[512]f | sip[512]f |
//   sw[320*64]ush | xs: 3 x 32768 x-slots (ph1) aliased by sBF[32768]ush (ph3)
#define OFF_SU 0
#define OFF_SV 1920
#define OFF_RP 3456
#define OFF_IP 5504
#define OFF_SW 7552
#define OFF_XS 48512
#define SMEM_BYTES 146816

// sw bank-swizzle (verified r0-r11)
__device__ __forceinline__ int swz(int row, int col) {
  return row * 64 + (col ^ ((((unsigned)row >> 2) & 3) << 4));
}

__global__ __launch_bounds__(512, 1) void k_fused(
    const float* __restrict__ x, const float* __restrict__ ipj,
    const float* __restrict__ irc, const float* __restrict__ rpj,
    const float* __restrict__ rrc, const float* __restrict__ Wr,
    const float* __restrict__ bias, float* __restrict__ out, int mode) {
  extern __shared__ __align__(16) char smem[];
  float* su = (float*)(smem + OFF_SU);
  float* sV = (float*)(smem + OFF_SV);
  float* srp = (float*)(smem + OFF_RP);
  float* sip = (float*)(smem + OFF_IP);
  unsigned short* sw = (unsigned short*)(smem + OFF_SW);
  unsigned short* sBF = (unsigned short*)(smem + OFF_XS);
  float* xsf = (float*)(smem + OFF_XS);

  const int tid = threadIdx.x;
  const int wv = tid >> 6;      // 0..7
  const int lane = tid & 63;
  const int b = blockIdx.x >> 3;
  const int g = blockIdx.x & 7;
  const int r0 = g * 256;

  // ---- top preloads ----
  f32x4 cv0 = *(const f32x4*)(irc + 4 * (lane & 7));
  f32x4 cv1 = *(const f32x4*)(irc + 4 * (lane & 7) + 32);
  f32x4 cv2 = *(const f32x4*)(irc + 4 * (lane & 7) + 64);
  f32x4 cv3 = *(const f32x4*)(irc + 4 * (lane & 7) + 96);
  float rpv[8], ipv[8], rrv[8];
  #pragma unroll
  for (int k = 0; k < 8; k++) {
    int h = lane + 64 * k;
    rpv[k] = rpj[h]; ipv[k] = ipj[h]; rrv[k] = 0.1f * rrc[h];
  }
  if (tid < 96) su[384 + tid] = 0.f;
  if (tid < 80) sV[304 + tid] = 0.f;

  // ---------------- Phase 1 (x8 when mode==1) ----------------
#define ISSUE(c) do { \
    int tc_ = r0 - 128 + (c) * 64 + wv * 8; if (tc_ < 0) tc_ = 0; \
    const float* gs_ = x + ((size_t)b * S_ + tc_) * I_ + lane * 4; \
    char* ld_ = (char*)xsf + ((c) % 3) * 32768 + wv * 4096; \
    gload16(gs_,       ld_); \
    gload16(gs_ + 256, ld_ + 1024); \
    gload16(gs_ + 512, ld_ + 2048); \
    gload16(gs_ + 768, ld_ + 3072); \
  } while (0)

#define COMPUTE(c) do { \
    const float* bp_ = xsf + ((c) % 3) * 8192 + (wv * 8 + (lane >> 3)) * 128 + (lane & 7) * 4; \
    f32x4 x0_ = *(const f32x4*)(bp_); \
    f32x4 x1_ = *(const f32x4*)(bp_ + 32); \
    f32x4 x2_ = *(const f32x4*)(bp_ + 64); \
    f32x4 x3_ = *(const f32x4*)(bp_ + 96); \
    float p0_ = x0_[0] * cv0[0], p1_ = x0_[1] * cv0[1]; \
    float p2_ = x0_[2] * cv0[2], p3_ = x0_[3] * cv0[3]; \
    p0_ = fmaf(x1_[0], cv1[0], p0_); p1_ = fmaf(x1_[1], cv1[1], p1_); \
    p2_ = fmaf(x1_[2], cv1[2], p2_); p3_ = fmaf(x1_[3], cv1[3], p3_); \
    p0_ = fmaf(x2_[0], cv2[0], p0_); p1_ = fmaf(x2_[1], cv2[1], p1_); \
    p2_ = fmaf(x2_[2], cv2[2], p2_); p3_ = fmaf(x2_[3], cv2[3], p3_); \
    p0_ = fmaf(x3_[0], cv3[0], p0_); p1_ = fmaf(x3_[1], cv3[1], p1_); \
    p2_ = fmaf(x3_[2], cv3[2], p2_); p3_ = fmaf(x3_[3], cv3[3], p3_); \
    float s_ = (p0_ + p1_) + (p2_ + p3_); \
    DPP_ADD(s_, 0x121); DPP_ADD(s_, 0x122); DPP_ADD(s_, 0x124); \
    float mask_ = (r0 - 128 + (c) * 64 >= 0) ? 1.f : 0.f; \
    if ((lane & 7) == 7) su[(c) * 64 + wv * 8 + (lane >> 3)] = s_ * mask_; \
  } while (0)

  {
    const int nrep = (mode == 1) ? 8 : 1;
    for (int rep = 0; rep < nrep; rep++) {
      ISSUE(0); ISSUE(1); ISSUE(2);
      WAITVM(8); COMPUTE(0); SCHEDB(); ISSUE(3);
      WAITVM(8); COMPUTE(1); SCHEDB(); ISSUE(4);
      WAITVM(8); COMPUTE(2); SCHEDB(); ISSUE(5);
      WAITVM(8); COMPUTE(3);
      WAITVM(4); COMPUTE(4);
      WAITVM(0); COMPUTE(5);
      __syncthreads();   // su complete; x slots dead
    }
  }
  if (mode == 1) return;

  // ---- su window -> 2 VGPRs (readlane broadcast) ----
  float suA = su[32 + wv * 38 + lane];
  float suB = su[32 + wv * 38 + 64 + lane];

  // ---- W preload to registers; frag map verified r0-r11 ----
  float4 wA0, wB0, wA1, wB1, wA2, wB2, wA3, wB3;
  float4 wA4, wB4, wA5, wB5, wA6, wB6, wA7, wB7;
#define WLOAD(m, A, Bv) do { \
    int seg_ = tid + 512 * (m); \
    int l2_ = seg_ & 63, ot_ = (seg_ >> 6) & 3, kt_ = seg_ >> 8; \
    const float4* wp_ = (const float4*)(Wr + (size_t)(ot_ * 16 + (l2_ & 15)) * H_ + kt_ * 32 + (l2_ >> 4) * 8); \
    A = wp_[0]; Bv = wp_[1]; \
  } while (0)
  WLOAD(0, wA0, wB0); WLOAD(1, wA1, wB1); WLOAD(2, wA2, wB2); WLOAD(3, wA3, wB3);
  WLOAD(4, wA4, wB4); WLOAD(5, wA5, wB5); WLOAD(6, wA6, wB6); WLOAD(7, wA7, wB7);
  float rpa = rpj[tid];
  float ipa = ipj[tid];

  // ---------------- Phase 2 (x8 when mode==2) ----------------
#define VSTEP(UT) do { \
    float ut_ = (UT); \
    float q0 = fmaxf(fmaf(v, rpv[0], ut_ * ipv[0]), 0.f) * rrv[0]; \
    float q1 = fmaxf(fmaf(v, rpv[1], ut_ * ipv[1]), 0.f) * rrv[1]; \
    float q2 = fmaxf(fmaf(v, rpv[2], ut_ * ipv[2]), 0.f) * rrv[2]; \
    float q3 = fmaxf(fmaf(v, rpv[3], ut_ * ipv[3]), 0.f) * rrv[3]; \
    float q4 = fmaxf(fmaf(v, rpv[4], ut_ * ipv[4]), 0.f) * rrv[4]; \
    float q5 = fmaxf(fmaf(v, rpv[5], ut_ * ipv[5]), 0.f) * rrv[5]; \
    float q6 = fmaxf(fmaf(v, rpv[6], ut_ * ipv[6]), 0.f) * rrv[6]; \
    float q7 = fmaxf(fmaf(v, rpv[7], ut_ * ipv[7]), 0.f) * rrv[7]; \
    float s_ = ((q0 + q1) + (q2 + q3)) + ((q4 + q5) + (q6 + q7)); \
    DPP_ADD(s_, 0x121); DPP_ADD(s_, 0x122); DPP_ADD(s_, 0x124); DPP_ADD(s_, 0x128); \
    DPP_ADD(s_, 0x142); DPP_ADD(s_, 0x143); \
    float tot_ = RL(s_, 63); \
    v = fmaf(0.9f, v, tot_); \
  } while (0)
  {
    const int nrep = (mode == 2) ? 8 : 1;
    for (int rep = 0; rep < nrep; rep++) {
      float v = 0.f;
      int base = wv * 38;
      #pragma unroll 8
      for (int i = 0; i < 48; i++) VSTEP(RL(suA, i));          // warm-up
      #pragma unroll 8
      for (int k = 0; k < 16; k++) {                           // real, su in A
        if (lane == 0) sV[base + k] = v;                       // v entering step
        VSTEP(RL(suA, 48 + k));
      }
      #pragma unroll 2
      for (int k = 16; k < 38; k++) {                          // real, su in B
        if (lane == 0) sV[base + k] = v;
        VSTEP(RL(suB, k - 16));
      }
      asm volatile("" ::: "memory");
    }
  }
  if (mode == 2) return;

  // ---- convert W regs -> sBF (aliases dead x slots), stage srp/sip ----
#define WPACK(m, A, Bv) do { \
    int seg_ = tid + 512 * (m); \
    uint4 pk_; \
    pk_.x = (unsigned)f2bf(A.x) | ((unsigned)f2bf(A.y) << 16); \
    pk_.y = (unsigned)f2bf(A.z) | ((unsigned)f2bf(A.w) << 16); \
    pk_.z = (unsigned)f2bf(Bv.x) | ((unsigned)f2bf(Bv.y) << 16); \
    pk_.w = (unsigned)f2bf(Bv.z) | ((unsigned)f2bf(Bv.w) << 16); \
    *(uint4*)(sBF + seg_ * 8) = pk_; \
  } while (0)
  WPACK(0, wA0, wB0); WPACK(1, wA1, wB1); WPACK(2, wA2, wB2); WPACK(3, wA3, wB3);
  WPACK(4, wA4, wB4); WPACK(5, wA5, wB5); WPACK(6, wA6, wB6); WPACK(7, wA7, wB7);
  srp[tid] = rpa;
  sip[tid] = ipa;
  __syncthreads();   // sV + sBF + srp/sip ready

  // ---------------- Phase 3 (x8 when mode==3) ----------------
  {
    const int nrep = (mode == 3) ? 8 : 1;
    for (int rep = 0; rep < nrep; rep++) {
      int tl = lane & 15, quad = lane >> 4;
      float Vr0 = sV[(wv * 3 + 0) * 16 + tl], ur0 = su[80 + (wv * 3 + 0) * 16 + tl];
      float Vr1 = sV[(wv * 3 + 1) * 16 + tl], ur1 = su[80 + (wv * 3 + 1) * 16 + tl];
      float Vr2 = sV[(wv * 3 + 2) * 16 + tl], ur2 = su[80 + (wv * 3 + 2) * 16 + tl];
      f32x4 acc[3][4] = {};  // [m][ot]
      #pragma unroll 4
      for (int kt = 0; kt < 16; kt++) {
        int hbase = kt * 32 + quad * 8;
        f32x4 rp4a = *(const f32x4*)(srp + hbase);
        f32x4 rp4b = *(const f32x4*)(srp + hbase + 4);
        f32x4 ip4a = *(const f32x4*)(sip + hbase);
        f32x4 ip4b = *(const f32x4*)(sip + hbase + 4);
        bf16x8 bfr0 = *(const bf16x8*)(sBF + (((kt * 4 + 0) * 64 + lane) << 3));
        bf16x8 bfr1 = *(const bf16x8*)(sBF + (((kt * 4 + 1) * 64 + lane) << 3));
        bf16x8 bfr2 = *(const bf16x8*)(sBF + (((kt * 4 + 2) * 64 + lane) << 3));
        bf16x8 bfr3 = *(const bf16x8*)(sBF + (((kt * 4 + 3) * 64 + lane) << 3));
        #pragma unroll
        for (int m = 0; m < 3; m++) {
          float Vm = m == 0 ? Vr0 : (m == 1 ? Vr1 : Vr2);
          float um = m == 0 ? ur0 : (m == 1 ? ur1 : ur2);
          float q[8];
          #pragma unroll
          for (int j = 0; j < 4; j++) {
            q[j]     = fmaxf(fmaf(Vm, rp4a[j], um * ip4a[j]), 0.f);
            q[4 + j] = fmaxf(fmaf(Vm, rp4b[j], um * ip4b[j]), 0.f);
          }
          union { bf16x8 v; unsigned w[4]; } a;
          #pragma unroll
          for (int j = 0; j < 4; j++) a.w[j] = pack_bf(q[2 * j], q[2 * j + 1]);
          acc[m][0] = __builtin_amdgcn_mfma_f32_16x16x32_bf16(a.v, bfr0, acc[m][0], 0, 0, 0);
          acc[m][1] = __builtin_amdgcn_mfma_f32_16x16x32_bf16(a.v, bfr1, acc[m][1], 0, 0, 0);
          acc[m][2] = __builtin_amdgcn_mfma_f32_16x16x32_bf16(a.v, bfr2, acc[m][2], 0, 0, 0);
          acc[m][3] = __builtin_amdgcn_mfma_f32_16x16x32_bf16(a.v, bfr3, acc[m][3], 0, 0, 0);
        }
      }
      // C/D layout: col = ot*16 + tl (o), row-in-tile = quad*4 + r (t offset)
      #pragma unroll
      for (int m = 0; m < 3; m++) {
        int mt = wv * 3 + m;
        if (mt < 19) {
          int rbase = mt * 16 + quad * 4;
          #pragma unroll
          for (int r = 0; r < 4; r++) {
            #pragma unroll
            for (int ot = 0; ot < 4; ot++)
              sw[swz(rbase + r, ot * 16 + tl)] = f2bf(acc[m][ot][r]);
          }
        }
      }
      asm volatile("" ::: "memory");
    }
  }
  __syncthreads();
  if (mode == 3) return;

  // ---------------- Phase 4 (x8 when mode==4) ----------------
  {
    const int nrep = (mode == 4) ? 8 : 1;
    for (int rep = 0; rep < nrep; rep++) {
      float y = 0.f;
      float bo = bias[lane];
      int k0 = wv * 32;
      float* ob = out + ((size_t)(b * S_ + r0 + k0)) * O_ + lane;
      #pragma unroll 8
      for (int i = 0; i < 48; i++)
        y = fmaf(0.9f, y, 0.1f * bf2f(sw[swz(k0 + i, lane)]));
      #pragma unroll 4
      for (int i = 0; i < 32; i++) {
        y = fmaf(0.9f, y, 0.1f * bf2f(sw[swz(k0 + 48 + i, lane)]));
        ob[(size_t)i * O_] = y + bo;
      }
      asm volatile("" ::: "memory");
    }
  }
}

extern "C" void kernel_launch(void* const* d_in, const int* in_sizes, int n_in,
                              void* d_out, int out_size, void* d_ws, size_t ws_size,
                              hipStream_t stream) {
  const float* x   = (const float*)d_in[0];
  const float* ipj = (const float*)d_in[1];
  const float* irc = (const float*)d_in[2];
  const float* rpj = (const float*)d_in[3];
  const float* rrc = (const float*)d_in[4];
  const float* Wr  = (const float*)d_in[5];
  const float* br  = (const float*)d_in[6];
  float* out = (float*)d_out;

  static bool s_init = false;
  if (!s_init) {
    hipFuncSetAttribute((const void*)k_fused,
                        hipFuncAttributeMaxDynamicSharedMemorySize, SMEM_BYTES);
    s_init = true;
  }
  // mode 0 first (correct out), then amplified phase probes (x8 re-execution,
  // all idempotent). Probe durations ~= ramp + 8*T_phase -> visible in top-5;
  // consecutive Dispatch_Ids identify modes.
  for (int mode = 0; mode <= 4; mode++)
    k_fused<<<dim3(256), dim3(512), SMEM_BYTES, stream>>>(x, ipj, irc, rpj, rrc,
                                                          Wr, br, out, mode);
}

// Round 14
// 114.318 us; speedup vs baseline: 3.8183x; 3.8183x over previous
//
#include <hip/hip_runtime.h>

// B=32, S=2048, I=128, H=512, O=64, R=1, ALPHA=0.1  (rank-1 scalar-state RNN)
// Single dispatch, 256 blocks x 512 threads (8 waves), 1 block/CU (143KB LDS).
// Block owns 256 output timesteps of one batch; recomputes 48-step warm-up.
// Round-12 ablation (amplified probes): ph2 ~= 15us of the 45us kernel and is
// ISSUE-bound at 2 chains/SIMD (VALUBusy 74%, ~75 VALU insts/step). This round
// wave-specializes ph2: waves 0-3 run 4 chains x 124 steps (1 chain/SIMD,
// halves scan issue pressure); waves 4-7 concurrently do the whole W pipeline
// (load W -> bf16 pack -> sBF, srp/sip staging) in their slack. ph1/ph3/ph4
// byte-identical to round-10 (verified, 116us).
// Round-13 lesson: WSEG macro local named B_ collided with the #define B_ 32
// -> compile failure. Locals renamed Wa_/Wb_.
//   ph1: u[t] = x[t,:].irc for t in [r0-128,r0+256); global_load_lds (16B),
//        counted vmcnt, 3-slot pipeline, per-wave stripes (no syncthreads)
//   ph2: waves 0-3: chains of 76 rows, 124 uniform steps (48 warm-up)
//        waves 4-7: W^T -> bf16 MFMA B-frags (16 segs each) + srp/sip
//   ph3: w rows [0,304) = relu(V*rp+u*ip) @ W^T via 16x16x32 bf16 MFMA -> sw
//   ph4: y-scan, 8 waves x 32 outputs, 48-step warm-up (w rows t<0 are zero)

#define B_ 32
#define S_ 2048
#define I_ 128
#define H_ 512
#define O_ 64

typedef __attribute__((ext_vector_type(8))) short bf16x8;
typedef __attribute__((ext_vector_type(4))) float f32x4;

__device__ __forceinline__ unsigned short f2bf(float f) {
  unsigned int b = __float_as_uint(f);
  b += 0x7FFFu + ((b >> 16) & 1u);
  return (unsigned short)(b >> 16);
}
__device__ __forceinline__ float bf2f(unsigned short s) {
  return __uint_as_float(((unsigned)s) << 16);
}
__device__ __forceinline__ unsigned pack_bf(float lo, float hi) {
  unsigned a = (__float_as_uint(lo) + 0x8000u) >> 16;
  unsigned b = (__float_as_uint(hi) + 0x8000u) & 0xFFFF0000u;
  return a | b;
}

// DPP add via update_dpp (verified r0-r12). 0x121/2/4/8 = row_ror 1/2/4/8;
// 0x142 = row_bcast15; 0x143 = row_bcast31. ror x4 + bcast15 + bcast31 ->
// lane63 = full 64-lane sum.
#define DPP_ADD(s, CTRL) \
  s += __int_as_float(__builtin_amdgcn_update_dpp(0, __float_as_int(s), CTRL, 0xF, 0xF, true))

#define RL(s, L) __int_as_float(__builtin_amdgcn_readlane(__float_as_int(s), (L)))

// async global->LDS, 16B/lane; LDS dest = uniform base + lane*16 (HW rule)
__device__ __forceinline__ void gload16(const void* g, void* l) {
  __builtin_amdgcn_global_load_lds(
      (const __attribute__((address_space(1))) unsigned int*)g,
      (__attribute__((address_space(3))) unsigned int*)l, 16, 0, 0);
}
#define WAITVM(N) asm volatile("s_waitcnt vmcnt(" #N ")" ::: "memory")
#define SCHEDB() __builtin_amdgcn_sched_barrier(0)

// LDS layout (bytes): su[480]f | sV[384]f | srp[512]f | sip[512]f |
//   sw[320*64]ush | xs: 3 x 32768 x-slots (ph1) aliased by sBF[32768]ush (ph3)
#define OFF_SU 0
#define OFF_SV 1920
#define OFF_RP 3456
#define OFF_IP 5504
#define OFF_SW 7552
#define OFF_XS 48512
#define SMEM_BYTES 146816

// sw bank-swizzle (verified r0-r12): row stride 128 B; XOR col bits 4-5 with
// (row>>2)&3 (== quad in ph3) spreads quads across banks.
__device__ __forceinline__ int swz(int row, int col) {
  return row * 64 + (col ^ ((((unsigned)row >> 2) & 3) << 4));
}

__global__ __launch_bounds__(512, 1) void k_fused(
    const float* __restrict__ x, const float* __restrict__ ipj,
    const float* __restrict__ irc, const float* __restrict__ rpj,
    const float* __restrict__ rrc, const float* __restrict__ Wr,
    const float* __restrict__ bias, float* __restrict__ out) {
  extern __shared__ __align__(16) char smem[];
  float* su = (float*)(smem + OFF_SU);
  float* sV = (float*)(smem + OFF_SV);
  float* srp = (float*)(smem + OFF_RP);
  float* sip = (float*)(smem + OFF_IP);
  unsigned short* sw = (unsigned short*)(smem + OFF_SW);
  unsigned short* sBF = (unsigned short*)(smem + OFF_XS);
  float* xsf = (float*)(smem + OFF_XS);

  const int tid = threadIdx.x;
  const int wv = tid >> 6;      // 0..7
  const int lane = tid & 63;
  const int b = blockIdx.x >> 3;
  const int g = blockIdx.x & 7;
  const int r0 = g * 256;

  // ---- top preloads (oldest in VMEM FIFO; retired by ph1's counted waits) ----
  // ph1 dot: lane handles row (wv*8 + (lane>>3)), col segs (lane&7)*4 + 32i
  f32x4 cv0 = *(const f32x4*)(irc + 4 * (lane & 7));
  f32x4 cv1 = *(const f32x4*)(irc + 4 * (lane & 7) + 32);
  f32x4 cv2 = *(const f32x4*)(irc + 4 * (lane & 7) + 64);
  f32x4 cv3 = *(const f32x4*)(irc + 4 * (lane & 7) + 96);
  // ph2 per-lane params, h = lane + 64k; 0.1 folded into rrv (r10-verified)
  float rpv[8], ipv[8], rrv[8];
  #pragma unroll
  for (int k = 0; k < 8; k++) {
    int h = lane + 64 * k;
    rpv[k] = rpj[h]; ipv[k] = ipj[h]; rrv[k] = 0.1f * rrc[h];
  }
  // zero pads: su[384..480) (suB tail lanes read it), sV[304..384)
  if (tid < 96) su[384 + tid] = 0.f;
  if (tid < 80) sV[304 + tid] = 0.f;

  // ---------------- Phase 1: x window [r0-128,r0+256) -> su via gll pipeline.
  // 6 chunks of 64 rows (32 KB). Wave stages its own rows [wv*8,+8) (4 glls,
  // 1 KB each) into slot c%3 and consumes only those -> no syncthreads needed.
  // ORDER INVARIANT (r6 bug): ISSUE(c+3) reuses slot c%3 -> must be emitted
  // AFTER COMPUTE(c)'s ds_reads. sched_barrier(0) pins compile order.
#define ISSUE(c) do { \
    int tc_ = r0 - 128 + (c) * 64 + wv * 8; if (tc_ < 0) tc_ = 0; \
    const float* gs_ = x + ((size_t)b * S_ + tc_) * I_ + lane * 4; \
    char* ld_ = (char*)xsf + ((c) % 3) * 32768 + wv * 4096; \
    gload16(gs_,       ld_); \
    gload16(gs_ + 256, ld_ + 1024); \
    gload16(gs_ + 512, ld_ + 2048); \
    gload16(gs_ + 768, ld_ + 3072); \
  } while (0)

#define COMPUTE(c) do { \
    const float* bp_ = xsf + ((c) % 3) * 8192 + (wv * 8 + (lane >> 3)) * 128 + (lane & 7) * 4; \
    f32x4 x0_ = *(const f32x4*)(bp_); \
    f32x4 x1_ = *(const f32x4*)(bp_ + 32); \
    f32x4 x2_ = *(const f32x4*)(bp_ + 64); \
    f32x4 x3_ = *(const f32x4*)(bp_ + 96); \
    float p0_ = x0_[0] * cv0[0], p1_ = x0_[1] * cv0[1]; \
    float p2_ = x0_[2] * cv0[2], p3_ = x0_[3] * cv0[3]; \
    p0_ = fmaf(x1_[0], cv1[0], p0_); p1_ = fmaf(x1_[1], cv1[1], p1_); \
    p2_ = fmaf(x1_[2], cv1[2], p2_); p3_ = fmaf(x1_[3], cv1[3], p3_); \
    p0_ = fmaf(x2_[0], cv2[0], p0_); p1_ = fmaf(x2_[1], cv2[1], p1_); \
    p2_ = fmaf(x2_[2], cv2[2], p2_); p3_ = fmaf(x2_[3], cv2[3], p3_); \
    p0_ = fmaf(x3_[0], cv3[0], p0_); p1_ = fmaf(x3_[1], cv3[1], p1_); \
    p2_ = fmaf(x3_[2], cv3[2], p2_); p3_ = fmaf(x3_[3], cv3[3], p3_); \
    float s_ = (p0_ + p1_) + (p2_ + p3_); \
    DPP_ADD(s_, 0x121); DPP_ADD(s_, 0x122); DPP_ADD(s_, 0x124); \
    float mask_ = (r0 - 128 + (c) * 64 >= 0) ? 1.f : 0.f; \
    if ((lane & 7) == 7) su[(c) * 64 + wv * 8 + (lane >> 3)] = s_ * mask_; \
  } while (0)

  ISSUE(0); ISSUE(1); ISSUE(2);
  WAITVM(8); COMPUTE(0); SCHEDB(); ISSUE(3);
  WAITVM(8); COMPUTE(1); SCHEDB(); ISSUE(4);
  WAITVM(8); COMPUTE(2); SCHEDB(); ISSUE(5);
  WAITVM(8); COMPUTE(3);
  WAITVM(4); COMPUTE(4);
  WAITVM(0); COMPUTE(5);
  __syncthreads();   // su complete; x slots dead

  // ---------------- Phase 2 (wave-specialized) ----------------
  if (wv < 4) {
    // Scan path: chain wv covers sV rows [wv*76, +76); 124 uniform steps
    // (48 warm-up). Step s consumes su[76*wv + 32 + s]; su window -> 2 VGPRs.
    // 1 chain/SIMD -> scan issue no longer contends with a sibling wave.
    float suA = su[76 * wv + 32 + lane];
    float suB = su[76 * wv + 96 + lane];   // max idx 387 < 480 (zero pad)
#define VSTEP(UT) do { \
    float ut_ = (UT); \
    float q0 = fmaxf(fmaf(v, rpv[0], ut_ * ipv[0]), 0.f) * rrv[0]; \
    float q1 = fmaxf(fmaf(v, rpv[1], ut_ * ipv[1]), 0.f) * rrv[1]; \
    float q2 = fmaxf(fmaf(v, rpv[2], ut_ * ipv[2]), 0.f) * rrv[2]; \
    float q3 = fmaxf(fmaf(v, rpv[3], ut_ * ipv[3]), 0.f) * rrv[3]; \
    float q4 = fmaxf(fmaf(v, rpv[4], ut_ * ipv[4]), 0.f) * rrv[4]; \
    float q5 = fmaxf(fmaf(v, rpv[5], ut_ * ipv[5]), 0.f) * rrv[5]; \
    float q6 = fmaxf(fmaf(v, rpv[6], ut_ * ipv[6]), 0.f) * rrv[6]; \
    float q7 = fmaxf(fmaf(v, rpv[7], ut_ * ipv[7]), 0.f) * rrv[7]; \
    float s_ = ((q0 + q1) + (q2 + q3)) + ((q4 + q5) + (q6 + q7)); \
    DPP_ADD(s_, 0x121); DPP_ADD(s_, 0x122); DPP_ADD(s_, 0x124); DPP_ADD(s_, 0x128); \
    DPP_ADD(s_, 0x142); DPP_ADD(s_, 0x143); \
    float tot_ = RL(s_, 63); \
    v = fmaf(0.9f, v, tot_); \
  } while (0)
    float v = 0.f;
    int base = wv * 76;
    #pragma unroll 8
    for (int i = 0; i < 48; i++) VSTEP(RL(suA, i));            // warm-up
    #pragma unroll 8
    for (int k = 0; k < 16; k++) {                             // real, su in A
      if (lane == 0) sV[base + k] = v;                         // v entering step
      VSTEP(RL(suA, 48 + k));
    }
    #pragma unroll 4
    for (int k = 16; k < 76; k++) {                            // real, su in B
      if (lane == 0) sV[base + k] = v;
      VSTEP(RL(suB, k - 16));
    }
  } else {
    // W path: waves 4-7 (256 threads) pack all 4096 B-frag segments.
    // Frag map (verified r0-r12):
    // sBF[((kt*4+ot)*64+l2)*8+j] = bf(W[(ot*16+(l2&15))*H + kt*32+(l2>>4)*8+j])
    int tid2 = tid - 256;   // 0..255
#define WSEG(m) do { \
    int seg_ = tid2 + 256 * (m); \
    int l2_ = seg_ & 63, ot_ = (seg_ >> 6) & 3, kt_ = seg_ >> 8; \
    const float4* wp_ = (const float4*)(Wr + (size_t)(ot_ * 16 + (l2_ & 15)) * H_ + kt_ * 32 + (l2_ >> 4) * 8); \
    float4 Wa_ = wp_[0], Wb_ = wp_[1]; \
    uint4 pk_; \
    pk_.x = (unsigned)f2bf(Wa_.x) | ((unsigned)f2bf(Wa_.y) << 16); \
    pk_.y = (unsigned)f2bf(Wa_.z) | ((unsigned)f2bf(Wa_.w) << 16); \
    pk_.z = (unsigned)f2bf(Wb_.x) | ((unsigned)f2bf(Wb_.y) << 16); \
    pk_.w = (unsigned)f2bf(Wb_.z) | ((unsigned)f2bf(Wb_.w) << 16); \
    *(uint4*)(sBF + seg_ * 8) = pk_; \
  } while (0)
    WSEG(0);  WSEG(1);  WSEG(2);  WSEG(3);
    WSEG(4);  WSEG(5);  WSEG(6);  WSEG(7);
    WSEG(8);  WSEG(9);  WSEG(10); WSEG(11);
    WSEG(12); WSEG(13); WSEG(14); WSEG(15);
    // srp/sip staging: 256 threads x 2 elements each (disjoint indices)
    srp[tid2] = rpj[tid2]; srp[tid2 + 256] = rpj[tid2 + 256];
    sip[tid2] = ipj[tid2]; sip[tid2 + 256] = ipj[tid2 + 256];
  }
  __syncthreads();   // sV + sBF + srp/sip ready

  // ---------------- Phase 3: w rows [0,304) via MFMA; 3 m-tiles/wave (mt<19).
  // sV row k <-> t = r0-48+k; matching u is su[80+k].
  {
    int tl = lane & 15, quad = lane >> 4;
    float Vr0 = sV[(wv * 3 + 0) * 16 + tl], ur0 = su[80 + (wv * 3 + 0) * 16 + tl];
    float Vr1 = sV[(wv * 3 + 1) * 16 + tl], ur1 = su[80 + (wv * 3 + 1) * 16 + tl];
    float Vr2 = sV[(wv * 3 + 2) * 16 + tl], ur2 = su[80 + (wv * 3 + 2) * 16 + tl];
    f32x4 acc[3][4] = {};  // [m][ot]
    #pragma unroll 4
    for (int kt = 0; kt < 16; kt++) {
      int hbase = kt * 32 + quad * 8;
      f32x4 rp4a = *(const f32x4*)(srp + hbase);
      f32x4 rp4b = *(const f32x4*)(srp + hbase + 4);
      f32x4 ip4a = *(const f32x4*)(sip + hbase);
      f32x4 ip4b = *(const f32x4*)(sip + hbase + 4);
      bf16x8 bfr0 = *(const bf16x8*)(sBF + (((kt * 4 + 0) * 64 + lane) << 3));
      bf16x8 bfr1 = *(const bf16x8*)(sBF + (((kt * 4 + 1) * 64 + lane) << 3));
      bf16x8 bfr2 = *(const bf16x8*)(sBF + (((kt * 4 + 2) * 64 + lane) << 3));
      bf16x8 bfr3 = *(const bf16x8*)(sBF + (((kt * 4 + 3) * 64 + lane) << 3));
      #pragma unroll
      for (int m = 0; m < 3; m++) {
        float Vm = m == 0 ? Vr0 : (m == 1 ? Vr1 : Vr2);
        float um = m == 0 ? ur0 : (m == 1 ? ur1 : ur2);
        float q[8];
        #pragma unroll
        for (int j = 0; j < 4; j++) {
          q[j]     = fmaxf(fmaf(Vm, rp4a[j], um * ip4a[j]), 0.f);
          q[4 + j] = fmaxf(fmaf(Vm, rp4b[j], um * ip4b[j]), 0.f);
        }
        union { bf16x8 v; unsigned w[4]; } a;
        #pragma unroll
        for (int j = 0; j < 4; j++) a.w[j] = pack_bf(q[2 * j], q[2 * j + 1]);
        acc[m][0] = __builtin_amdgcn_mfma_f32_16x16x32_bf16(a.v, bfr0, acc[m][0], 0, 0, 0);
        acc[m][1] = __builtin_amdgcn_mfma_f32_16x16x32_bf16(a.v, bfr1, acc[m][1], 0, 0, 0);
        acc[m][2] = __builtin_amdgcn_mfma_f32_16x16x32_bf16(a.v, bfr2, acc[m][2], 0, 0, 0);
        acc[m][3] = __builtin_amdgcn_mfma_f32_16x16x32_bf16(a.v, bfr3, acc[m][3], 0, 0, 0);
      }
    }
    // C/D layout: col = ot*16 + tl (o), row-in-tile = quad*4 + r (t offset)
    #pragma unroll
    for (int m = 0; m < 3; m++) {
      int mt = wv * 3 + m;
      if (mt < 19) {
        int rbase = mt * 16 + quad * 4;
        #pragma unroll
        for (int r = 0; r < 4; r++) {
          #pragma unroll
          for (int ot = 0; ot < 4; ot++)
            sw[swz(rbase + r, ot * 16 + tl)] = f2bf(acc[m][ot][r]);
        }
      }
    }
  }
  __syncthreads();

  // ---------------- Phase 4: y-scan. Wave wv owns outputs [r0+wv*32,+32);
  // scans sw rows [wv*32,+80) = 48 warm + 32 real (rows with t<0 are zero).
  {
    float y = 0.f;
    float bo = bias[lane];
    int k0 = wv * 32;
    float* ob = out + ((size_t)(b * S_ + r0 + k0)) * O_ + lane;
    #pragma unroll 8
    for (int i = 0; i < 48; i++)
      y = fmaf(0.9f, y, 0.1f * bf2f(sw[swz(k0 + i, lane)]));
    #pragma unroll 4
    for (int i = 0; i < 32; i++) {
      y = fmaf(0.9f, y, 0.1f * bf2f(sw[swz(k0 + 48 + i, lane)]));
      ob[(size_t)i * O_] = y + bo;
    }
  }
}

extern "C" void kernel_launch(void* const* d_in, const int* in_sizes, int n_in,
                              void* d_out, int out_size, void* d_ws, size_t ws_size,
                              hipStream_t stream) {
  const float* x   = (const float*)d_in[0];
  const float* ipj = (const float*)d_in[1];
  const float* irc = (const float*)d_in[2];
  const float* rpj = (const float*)d_in[3];
  const float* rrc = (const float*)d_in[4];
  const float* Wr  = (const float*)d_in[5];
  const float* br  = (const float*)d_in[6];
  float* out = (float*)d_out;

  static bool s_init = false;
  if (!s_init) {
    hipFuncSetAttribute((const void*)k_fused,
                        hipFuncAttributeMaxDynamicSharedMemorySize, SMEM_BYTES);
    s_init = true;
  }
  k_fused<<<dim3(256), dim3(512), SMEM_BYTES, stream>>>(x, ipj, irc, rpj, rrc,
                                                        Wr, br, out);
}

// Round 15
// 110.254 us; speedup vs baseline: 3.9590x; 1.0369x over previous
//
#include <hip/hip_runtime.h>

// B=32, S=2048, I=128, H=512, O=64, R=1, ALPHA=0.1  (rank-1 scalar-state RNN)
// Single dispatch, 256 blocks x 512 threads (8 waves), 1 block/CU (143KB LDS).
// Block owns 256 output timesteps of one batch; recomputes warm-up.
// r12 ablation: T2 (V-scan) = 12.1us, issue+chain bound (~75 VALU/step).
// r14: wave-specialized scan (1 chain/SIMD) -> ~10.8us, latency-coupled.
// r15 (this): per-step 75 -> ~41 insts + shorter chain:
//   - med3 fold (r5-verified math): q = fmed3(fma(v,a,ut*b), lo, hi) with
//     a=0.1*rr*rp, b=0.1*rr*ip, (lo,hi)=(0,inf)/( -inf,0) by sign(rr)
//   - fused DPP reduce: v_add_f32_dpp x6 (ror 1/2/4/8 + bcast15/31, AMD masks)
//   - V-warm 48->32 (err ~2e-5 through dw/dv; Y-warm stays 48): 108 steps
//   - v_cvt_pk_bf16_f32 replaces 5-inst pack_bf in ph3 A-frags + WSEG
//   - ph4: 0.1 folded into final scale
//   ph1: u[t] = x[t,:].irc for t in [r0-128,r0+256); global_load_lds (16B),
//        counted vmcnt, 3-slot pipeline, per-wave stripes (no syncthreads)
//   ph2: waves 0-3: chains of 76 rows, 108 uniform steps (32 warm-up)
//        waves 4-7: W^T -> bf16 MFMA B-frags (16 segs each) + srp/sip
//   ph3: w rows [0,304) = relu(V*rp+u*ip) @ W^T via 16x16x32 bf16 MFMA -> sw
//   ph4: y-scan, 8 waves x 32 outputs, 48-step warm-up (w rows t<0 are zero)

#define B_ 32
#define S_ 2048
#define I_ 128
#define H_ 512
#define O_ 64

typedef __attribute__((ext_vector_type(8))) short bf16x8;
typedef __attribute__((ext_vector_type(4))) float f32x4;

__device__ __forceinline__ unsigned short f2bf(float f) {
  unsigned int b = __float_as_uint(f);
  b += 0x7FFFu + ((b >> 16) & 1u);
  return (unsigned short)(b >> 16);
}
__device__ __forceinline__ float bf2f(unsigned short s) {
  return __uint_as_float(((unsigned)s) << 16);
}
// 2x f32 -> packed bf16 (RNE) in one instruction (T12 recipe; no builtin)
__device__ __forceinline__ unsigned cvtpk(float lo, float hi) {
  unsigned r;
  asm("v_cvt_pk_bf16_f32 %0, %1, %2" : "=v"(r) : "v"(lo), "v"(hi));
  return r;
}

// DPP add via update_dpp (verified r0-r14; used in ph1 only now).
#define DPP_ADD(s, CTRL) \
  s += __int_as_float(__builtin_amdgcn_update_dpp(0, __float_as_int(s), CTRL, 0xF, 0xF, true))

// Fused one-inst-per-stage wave64 sum (scan hot loop). Encodings 0x121/2/4/8 +
// 0x142/0x143 are HW-verified by r9-r14's update_dpp path; this is the same
// dataflow with the add fused (syntax = LLVM's own printed DPP form; masks per
// AMD canonical reduction: bcast15 writes rows 1,3; bcast31 writes rows 2,3).
// After the 6 stages lane63 = full 64-lane sum.
#define DPP_RED(s) do { \
  asm("v_add_f32_dpp %0, %0, %0 row_ror:1 row_mask:0xf bank_mask:0xf bound_ctrl:0" : "+v"(s)); \
  asm("v_add_f32_dpp %0, %0, %0 row_ror:2 row_mask:0xf bank_mask:0xf bound_ctrl:0" : "+v"(s)); \
  asm("v_add_f32_dpp %0, %0, %0 row_ror:4 row_mask:0xf bank_mask:0xf bound_ctrl:0" : "+v"(s)); \
  asm("v_add_f32_dpp %0, %0, %0 row_ror:8 row_mask:0xf bank_mask:0xf bound_ctrl:0" : "+v"(s)); \
  asm("v_add_f32_dpp %0, %0, %0 row_bcast:15 row_mask:0xa bank_mask:0xf" : "+v"(s)); \
  asm("v_add_f32_dpp %0, %0, %0 row_bcast:31 row_mask:0xc bank_mask:0xf" : "+v"(s)); \
} while (0)

#define RL(s, L) __int_as_float(__builtin_amdgcn_readlane(__float_as_int(s), (L)))

// async global->LDS, 16B/lane; LDS dest = uniform base + lane*16 (HW rule)
__device__ __forceinline__ void gload16(const void* g, void* l) {
  __builtin_amdgcn_global_load_lds(
      (const __attribute__((address_space(1))) unsigned int*)g,
      (__attribute__((address_space(3))) unsigned int*)l, 16, 0, 0);
}
#define WAITVM(N) asm volatile("s_waitcnt vmcnt(" #N ")" ::: "memory")
#define SCHEDB() __builtin_amdgcn_sched_barrier(0)

// LDS layout (bytes): su[480]f | sV[384]f | srp[512]f | sip[512]f |
//   sw[320*64]ush | xs: 3 x 32768 x-slots (ph1) aliased by sBF[32768]ush (ph3)
#define OFF_SU 0
#define OFF_SV 1920
#define OFF_RP 3456
#define OFF_IP 5504
#define OFF_SW 7552
#define OFF_XS 48512
#define SMEM_BYTES 146816

// sw bank-swizzle (verified r0-r14): row stride 128 B; XOR col bits 4-5 with
// (row>>2)&3 (== quad in ph3) spreads quads across banks.
__device__ __forceinline__ int swz(int row, int col) {
  return row * 64 + (col ^ ((((unsigned)row >> 2) & 3) << 4));
}

__global__ __launch_bounds__(512, 1) void k_fused(
    const float* __restrict__ x, const float* __restrict__ ipj,
    const float* __restrict__ irc, const float* __restrict__ rpj,
    const float* __restrict__ rrc, const float* __restrict__ Wr,
    const float* __restrict__ bias, float* __restrict__ out) {
  extern __shared__ __align__(16) char smem[];
  float* su = (float*)(smem + OFF_SU);
  float* sV = (float*)(smem + OFF_SV);
  float* srp = (float*)(smem + OFF_RP);
  float* sip = (float*)(smem + OFF_IP);
  unsigned short* sw = (unsigned short*)(smem + OFF_SW);
  unsigned short* sBF = (unsigned short*)(smem + OFF_XS);
  float* xsf = (float*)(smem + OFF_XS);

  const int tid = threadIdx.x;
  const int wv = tid >> 6;      // 0..7
  const int lane = tid & 63;
  const int b = blockIdx.x >> 3;
  const int g = blockIdx.x & 7;
  const int r0 = g * 256;

  // ---- top preloads (oldest in VMEM FIFO; retired by ph1's counted waits) ----
  // ph1 dot: lane handles row (wv*8 + (lane>>3)), col segs (lane&7)*4 + 32i
  f32x4 cv0 = *(const f32x4*)(irc + 4 * (lane & 7));
  f32x4 cv1 = *(const f32x4*)(irc + 4 * (lane & 7) + 32);
  f32x4 cv2 = *(const f32x4*)(irc + 4 * (lane & 7) + 64);
  f32x4 cv3 = *(const f32x4*)(irc + 4 * (lane & 7) + 96);
  // ph2 per-lane params, h = lane + 64k. med3 fold (r5-verified math):
  // 0.1*rr*relu(rp*v+ip*u) = fmed3(a*v+b*u, lo, hi), a=0.1*rr*rp, b=0.1*rr*ip,
  // (lo,hi) = (0,+inf) if rr>0 else (-inf,0).
  float av[8], bv[8], lo_[8], hi_[8];
  #pragma unroll
  for (int k = 0; k < 8; k++) {
    int h = lane + 64 * k;
    float rr = rrc[h], sc = 0.1f * rr;
    av[k] = rpj[h] * sc;
    bv[k] = ipj[h] * sc;
    lo_[k] = rr > 0.f ? 0.f : -__builtin_inff();
    hi_[k] = rr > 0.f ? __builtin_inff() : 0.f;
  }
  // zero pads: su[384..480) (suB tail lanes read it), sV[304..384)
  if (tid < 96) su[384 + tid] = 0.f;
  if (tid < 80) sV[304 + tid] = 0.f;

  // ---------------- Phase 1: x window [r0-128,r0+256) -> su via gll pipeline.
  // 6 chunks of 64 rows (32 KB). Wave stages its own rows [wv*8,+8) (4 glls,
  // 1 KB each) into slot c%3 and consumes only those -> no syncthreads needed.
  // ORDER INVARIANT (r6 bug): ISSUE(c+3) reuses slot c%3 -> must be emitted
  // AFTER COMPUTE(c)'s ds_reads. sched_barrier(0) pins compile order.
#define ISSUE(c) do { \
    int tc_ = r0 - 128 + (c) * 64 + wv * 8; if (tc_ < 0) tc_ = 0; \
    const float* gs_ = x + ((size_t)b * S_ + tc_) * I_ + lane * 4; \
    char* ld_ = (char*)xsf + ((c) % 3) * 32768 + wv * 4096; \
    gload16(gs_,       ld_); \
    gload16(gs_ + 256, ld_ + 1024); \
    gload16(gs_ + 512, ld_ + 2048); \
    gload16(gs_ + 768, ld_ + 3072); \
  } while (0)

#define COMPUTE(c) do { \
    const float* bp_ = xsf + ((c) % 3) * 8192 + (wv * 8 + (lane >> 3)) * 128 + (lane & 7) * 4; \
    f32x4 x0_ = *(const f32x4*)(bp_); \
    f32x4 x1_ = *(const f32x4*)(bp_ + 32); \
    f32x4 x2_ = *(const f32x4*)(bp_ + 64); \
    f32x4 x3_ = *(const f32x4*)(bp_ + 96); \
    float p0_ = x0_[0] * cv0[0], p1_ = x0_[1] * cv0[1]; \
    float p2_ = x0_[2] * cv0[2], p3_ = x0_[3] * cv0[3]; \
    p0_ = fmaf(x1_[0], cv1[0], p0_); p1_ = fmaf(x1_[1], cv1[1], p1_); \
    p2_ = fmaf(x1_[2], cv1[2], p2_); p3_ = fmaf(x1_[3], cv1[3], p3_); \
    p0_ = fmaf(x2_[0], cv2[0], p0_); p1_ = fmaf(x2_[1], cv2[1], p1_); \
    p2_ = fmaf(x2_[2], cv2[2], p2_); p3_ = fmaf(x2_[3], cv2[3], p3_); \
    p0_ = fmaf(x3_[0], cv3[0], p0_); p1_ = fmaf(x3_[1], cv3[1], p1_); \
    p2_ = fmaf(x3_[2], cv3[2], p2_); p3_ = fmaf(x3_[3], cv3[3], p3_); \
    float s_ = (p0_ + p1_) + (p2_ + p3_); \
    DPP_ADD(s_, 0x121); DPP_ADD(s_, 0x122); DPP_ADD(s_, 0x124); \
    float mask_ = (r0 - 128 + (c) * 64 >= 0) ? 1.f : 0.f; \
    if ((lane & 7) == 7) su[(c) * 64 + wv * 8 + (lane >> 3)] = s_ * mask_; \
  } while (0)

  ISSUE(0); ISSUE(1); ISSUE(2);
  WAITVM(8); COMPUTE(0); SCHEDB(); ISSUE(3);
  WAITVM(8); COMPUTE(1); SCHEDB(); ISSUE(4);
  WAITVM(8); COMPUTE(2); SCHEDB(); ISSUE(5);
  WAITVM(8); COMPUTE(3);
  WAITVM(4); COMPUTE(4);
  WAITVM(0); COMPUTE(5);
  __syncthreads();   // su complete; x slots dead

  // ---------------- Phase 2 (wave-specialized) ----------------
  if (wv < 4) {
    // Scan path: chain wv covers sV rows [wv*76, +76); 108 uniform steps
    // (32 warm-up). Step s consumes su[76*wv + 48 + s]; window -> 2 VGPRs.
    float suA = su[76 * wv + 48 + lane];
    float suB = su[76 * wv + 112 + lane];  // max idx 403 < 480 (zero pad)
#define VSTEP(UT) do { \
    float ut_ = (UT); \
    float x0 = fmaf(v, av[0], ut_ * bv[0]); \
    float x1 = fmaf(v, av[1], ut_ * bv[1]); \
    float x2 = fmaf(v, av[2], ut_ * bv[2]); \
    float x3 = fmaf(v, av[3], ut_ * bv[3]); \
    float x4 = fmaf(v, av[4], ut_ * bv[4]); \
    float x5 = fmaf(v, av[5], ut_ * bv[5]); \
    float x6 = fmaf(v, av[6], ut_ * bv[6]); \
    float x7 = fmaf(v, av[7], ut_ * bv[7]); \
    float q0 = __builtin_amdgcn_fmed3f(x0, lo_[0], hi_[0]); \
    float q1 = __builtin_amdgcn_fmed3f(x1, lo_[1], hi_[1]); \
    float q2 = __builtin_amdgcn_fmed3f(x2, lo_[2], hi_[2]); \
    float q3 = __builtin_amdgcn_fmed3f(x3, lo_[3], hi_[3]); \
    float q4 = __builtin_amdgcn_fmed3f(x4, lo_[4], hi_[4]); \
    float q5 = __builtin_amdgcn_fmed3f(x5, lo_[5], hi_[5]); \
    float q6 = __builtin_amdgcn_fmed3f(x6, lo_[6], hi_[6]); \
    float q7 = __builtin_amdgcn_fmed3f(x7, lo_[7], hi_[7]); \
    float s_ = ((q0 + q1) + (q2 + q3)) + ((q4 + q5) + (q6 + q7)); \
    DPP_RED(s_); \
    float tot_ = RL(s_, 63); \
    v = fmaf(0.9f, v, tot_); \
  } while (0)
    float v = 0.f;
    int base = wv * 76;
    #pragma unroll 8
    for (int i = 0; i < 32; i++) VSTEP(RL(suA, i));            // warm-up
    #pragma unroll 8
    for (int k = 0; k < 32; k++) {                             // real, su in A
      if (lane == 0) sV[base + k] = v;                         // v entering step
      VSTEP(RL(suA, 32 + k));
    }
    #pragma unroll 4
    for (int k = 32; k < 76; k++) {                            // real, su in B
      if (lane == 0) sV[base + k] = v;
      VSTEP(RL(suB, k - 32));
    }
  } else {
    // W path: waves 4-7 (256 threads) pack all 4096 B-frag segments.
    // Frag map (verified r0-r14):
    // sBF[((kt*4+ot)*64+l2)*8+j] = bf(W[(ot*16+(l2&15))*H + kt*32+(l2>>4)*8+j])
    int tid2 = tid - 256;   // 0..255
#define WSEG(m) do { \
    int seg_ = tid2 + 256 * (m); \
    int l2_ = seg_ & 63, ot_ = (seg_ >> 6) & 3, kt_ = seg_ >> 8; \
    const float4* wp_ = (const float4*)(Wr + (size_t)(ot_ * 16 + (l2_ & 15)) * H_ + kt_ * 32 + (l2_ >> 4) * 8); \
    float4 Wa_ = wp_[0], Wb_ = wp_[1]; \
    uint4 pk_; \
    pk_.x = cvtpk(Wa_.x, Wa_.y); \
    pk_.y = cvtpk(Wa_.z, Wa_.w); \
    pk_.z = cvtpk(Wb_.x, Wb_.y); \
    pk_.w = cvtpk(Wb_.z, Wb_.w); \
    *(uint4*)(sBF + seg_ * 8) = pk_; \
  } while (0)
    WSEG(0);  WSEG(1);  WSEG(2);  WSEG(3);
    WSEG(4);  WSEG(5);  WSEG(6);  WSEG(7);
    WSEG(8);  WSEG(9);  WSEG(10); WSEG(11);
    WSEG(12); WSEG(13); WSEG(14); WSEG(15);
    // srp/sip staging: 256 threads x 2 elements each (disjoint indices)
    srp[tid2] = rpj[tid2]; srp[tid2 + 256] = rpj[tid2 + 256];
    sip[tid2] = ipj[tid2]; sip[tid2 + 256] = ipj[tid2 + 256];
  }
  __syncthreads();   // sV + sBF + srp/sip ready

  // ---------------- Phase 3: w rows [0,304) via MFMA; 3 m-tiles/wave (mt<19).
  // sV row k <-> t = r0-48+k; matching u is su[80+k].
  {
    int tl = lane & 15, quad = lane >> 4;
    float Vr0 = sV[(wv * 3 + 0) * 16 + tl], ur0 = su[80 + (wv * 3 + 0) * 16 + tl];
    float Vr1 = sV[(wv * 3 + 1) * 16 + tl], ur1 = su[80 + (wv * 3 + 1) * 16 + tl];
    float Vr2 = sV[(wv * 3 + 2) * 16 + tl], ur2 = su[80 + (wv * 3 + 2) * 16 + tl];
    f32x4 acc[3][4] = {};  // [m][ot]
    #pragma unroll 4
    for (int kt = 0; kt < 16; kt++) {
      int hbase = kt * 32 + quad * 8;
      f32x4 rp4a = *(const f32x4*)(srp + hbase);
      f32x4 rp4b = *(const f32x4*)(srp + hbase + 4);
      f32x4 ip4a = *(const f32x4*)(sip + hbase);
      f32x4 ip4b = *(const f32x4*)(sip + hbase + 4);
      bf16x8 bfr0 = *(const bf16x8*)(sBF + (((kt * 4 + 0) * 64 + lane) << 3));
      bf16x8 bfr1 = *(const bf16x8*)(sBF + (((kt * 4 + 1) * 64 + lane) << 3));
      bf16x8 bfr2 = *(const bf16x8*)(sBF + (((kt * 4 + 2) * 64 + lane) << 3));
      bf16x8 bfr3 = *(const bf16x8*)(sBF + (((kt * 4 + 3) * 64 + lane) << 3));
      #pragma unroll
      for (int m = 0; m < 3; m++) {
        float Vm = m == 0 ? Vr0 : (m == 1 ? Vr1 : Vr2);
        float um = m == 0 ? ur0 : (m == 1 ? ur1 : ur2);
        float q[8];
        #pragma unroll
        for (int j = 0; j < 4; j++) {
          q[j]     = fmaxf(fmaf(Vm, rp4a[j], um * ip4a[j]), 0.f);
          q[4 + j] = fmaxf(fmaf(Vm, rp4b[j], um * ip4b[j]), 0.f);
        }
        union { bf16x8 v; unsigned w[4]; } a;
        #pragma unroll
        for (int j = 0; j < 4; j++) a.w[j] = cvtpk(q[2 * j], q[2 * j + 1]);
        acc[m][0] = __builtin_amdgcn_mfma_f32_16x16x32_bf16(a.v, bfr0, acc[m][0], 0, 0, 0);
        acc[m][1] = __builtin_amdgcn_mfma_f32_16x16x32_bf16(a.v, bfr1, acc[m][1], 0, 0, 0);
        acc[m][2] = __builtin_amdgcn_mfma_f32_16x16x32_bf16(a.v, bfr2, acc[m][2], 0, 0, 0);
        acc[m][3] = __builtin_amdgcn_mfma_f32_16x16x32_bf16(a.v, bfr3, acc[m][3], 0, 0, 0);
      }
    }
    // C/D layout: col = ot*16 + tl (o), row-in-tile = quad*4 + r (t offset)
    #pragma unroll
    for (int m = 0; m < 3; m++) {
      int mt = wv * 3 + m;
      if (mt < 19) {
        int rbase = mt * 16 + quad * 4;
        #pragma unroll
        for (int r = 0; r < 4; r++) {
          #pragma unroll
          for (int ot = 0; ot < 4; ot++)
            sw[swz(rbase + r, ot * 16 + tl)] = f2bf(acc[m][ot][r]);
        }
      }
    }
  }
  __syncthreads();

  // ---------------- Phase 4: y-scan. Wave wv owns outputs [r0+wv*32,+32);
  // scans sw rows [wv*32,+80) = 48 warm + 32 real (rows with t<0 are zero).
  // 0.1 folded into the final scale: y' = sum 0.9^k w; out = 0.1*y' + bias.
  {
    float y = 0.f;
    float bo = bias[lane];
    int k0 = wv * 32;
    float* ob = out + ((size_t)(b * S_ + r0 + k0)) * O_ + lane;
    #pragma unroll 8
    for (int i = 0; i < 48; i++)
      y = fmaf(0.9f, y, bf2f(sw[swz(k0 + i, lane)]));
    #pragma unroll 4
    for (int i = 0; i < 32; i++) {
      y = fmaf(0.9f, y, bf2f(sw[swz(k0 + 48 + i, lane)]));
      ob[(size_t)i * O_] = fmaf(0.1f, y, bo);
    }
  }
}

extern "C" void kernel_launch(void* const* d_in, const int* in_sizes, int n_in,
                              void* d_out, int out_size, void* d_ws, size_t ws_size,
                              hipStream_t stream) {
  const float* x   = (const float*)d_in[0];
  const float* ipj = (const float*)d_in[1];
  const float* irc = (const float*)d_in[2];
  const float* rpj = (const float*)d_in[3];
  const float* rrc = (const float*)d_in[4];
  const float* Wr  = (const float*)d_in[5];
  const float* br  = (const float*)d_in[6];
  float* out = (float*)d_out;

  static bool s_init = false;
  if (!s_init) {
    hipFuncSetAttribute((const void*)k_fused,
                        hipFuncAttributeMaxDynamicSharedMemorySize, SMEM_BYTES);
    s_init = true;
  }
  k_fused<<<dim3(256), dim3(512), SMEM_BYTES, stream>>>(x, ipj, irc, rpj, rrc,
                                                        Wr, br, out);
}